// Round 18
// baseline (269.887 us; speedup 1.0000x reference)
//
#include <hip/hip_runtime.h>
#include <hip/hip_bf16.h>
#include <math.h>

typedef __bf16 bf16;
typedef bf16 bf16x8 __attribute__((ext_vector_type(8)));
typedef bf16 bf16x4 __attribute__((ext_vector_type(4)));
typedef float f32x4 __attribute__((ext_vector_type(4)));

constexpr int DIM   = 256;
constexpr int NH    = 8;
constexpr int LTOT  = 112 * 112;        // 12544
constexpr int BTOT  = 4;
constexpr int MROWS = BTOT * LTOT;      // 50176
constexpr int MQKV  = MROWS + BTOT * 3; // 50188
constexpr int NTOK  = 49;
constexpr int NKV   = 52;

// ---------------- fused prologue: weight cvt + (pool partials + LN1 per 64-row chunk) ----
// grid = 1536 (cvt) + 784 (pool+ln1), 512 threads.
// pool+ln1 fusion: both touch the same 64 x-rows -> single HBM pass (LN1 reads are L1/L2-hot).
__global__ __launch_bounds__(512) void prologue(
    const float* __restrict__ qkvw, const float* __restrict__ projw,
    const float* __restrict__ fc1w, const float* __restrict__ fc2w,
    bf16* __restrict__ wdst,
    const float* __restrict__ x, const float* __restrict__ afg,
    const float* __restrict__ abg, const float* __restrict__ auk,
    float* __restrict__ pnum, float* __restrict__ pden,
    const float* __restrict__ g, const float* __restrict__ bt,
    bf16* __restrict__ xn)
{
    const int blk = blockIdx.x;
    const int tid = threadIdx.x;
    if (blk < 1536) {                            // ---- weight conversion ----
        int i = blk * 512 + tid;
        float v;
        if (i < 196608)      v = qkvw[i];
        else if (i < 262144) v = projw[i - 196608];
        else if (i < 524288) v = fc1w[i - 262144];
        else                 v = fc2w[i - 524288];
        wdst[i] = (bf16)v;
        return;
    }
    // ---- pool partials + LN1 for one 64-row chunk ----
    const int pb = blk - 1536;                   // 0..783
    const int b = pb / 196, ch = pb % 196;
    const int p0 = ch * 64;
    __shared__ float su[64], sf[64], sb[64];
    __shared__ float part[768];
    if (tid < 64) {
        int p = p0 + tid;
        su[tid] = auk[b * LTOT + p];
        sf[tid] = afg[b * LTOT + p];
        sb[tid] = abg[b * LTOT + p];
    }
    __syncthreads();
    {
        const int c = tid & 255;
        const int hseg = tid >> 8;               // 0: positions 0-31, 1: 32-63
        const int pbase = hseg * 32;
        float nu = 0.f, nf = 0.f, nb = 0.f;
        const float* xp = x + ((size_t)b * LTOT + p0 + pbase) * DIM + c;
        for (int pp = 0; pp < 32; ++pp) {
            float xv = xp[(size_t)pp * DIM];
            nu += su[pbase + pp] * xv;
            nf += sf[pbase + pp] * xv;
            nb += sb[pbase + pp] * xv;
        }
        if (hseg) { part[c] = nu; part[256 + c] = nf; part[512 + c] = nb; }
        __syncthreads();
        if (!hseg) {
            nu += part[c]; nf += part[256 + c]; nb += part[512 + c];
            size_t base = (size_t)pb * 3 * DIM + c;
            pnum[base]           = nu;
            pnum[base + DIM]     = nf;
            pnum[base + 2 * DIM] = nb;
            if (c < 3) {
                const float* sptr = c == 0 ? su : (c == 1 ? sf : sb);
                float t = 0.f;
                for (int i = 0; i < 64; ++i) t += sptr[i];
                pden[pb * 3 + c] = t;
            }
        }
    }
    __syncthreads();
    // ---- LN1 for the same 64 rows: 8 waves x 8 rows (x hot in cache) ----
    const int lane = tid & 63;
    const f32x4 gv = *(const f32x4*)(g + lane * 4);
    const f32x4 bv = *(const f32x4*)(bt + lane * 4);
    #pragma unroll
    for (int it = 0; it < 8; ++it) {
        const size_t row = (size_t)b * LTOT + p0 + (tid >> 6) * 8 + it;
        f32x4 v = *(const f32x4*)(x + row * DIM + lane * 4);
        float s  = v[0] + v[1] + v[2] + v[3];
        float s2 = v[0]*v[0] + v[1]*v[1] + v[2]*v[2] + v[3]*v[3];
        #pragma unroll
        for (int o = 32; o >= 1; o >>= 1) { s += __shfl_xor(s, o); s2 += __shfl_xor(s2, o); }
        float mu = s * (1.f / 256.f);
        float var = s2 * (1.f / 256.f) - mu * mu;
        float rs = rsqrtf(var + 1e-5f);
        bf16x4 o;
        #pragma unroll
        for (int u = 0; u < 4; ++u) o[u] = (bf16)((v[u] - mu) * rs * gv[u] + bv[u]);
        *(bf16x4*)(xn + row * DIM + lane * 4) = o;
    }
}

// ---------------- block LN helper (256 threads, one row) ----------------
__device__ __forceinline__ void block_meanvar(float v, float& mu, float& rstd, float eps) {
    float s = v, s2 = v * v;
    #pragma unroll
    for (int o = 32; o >= 1; o >>= 1) { s += __shfl_down(s, o); s2 += __shfl_down(s2, o); }
    __shared__ float ps[4], ps2[4];
    int w = threadIdx.x >> 6, ln = threadIdx.x & 63;
    if (ln == 0) { ps[w] = s; ps2[w] = s2; }
    __syncthreads();
    float S  = ps[0] + ps[1] + ps[2] + ps[3];
    float S2 = ps2[0] + ps2[1] + ps2[2] + ps2[3];
    mu = S * (1.f / 256.f);
    float var = S2 * (1.f / 256.f) - mu * mu;
    rstd = rsqrtf(var + eps);
}

// ---------------- prior reduce + LN1 -> xn rows [MROWS..MQKV) ----------------
__global__ __launch_bounds__(256) void prior_ln(
    const float* __restrict__ pnum, const float* __restrict__ pden,
    const float* __restrict__ g, const float* __restrict__ bt, bf16* __restrict__ xn)
{
    int b = blockIdx.x / 3, j = blockIdx.x % 3, tid = threadIdx.x;
    float s = 0.f, den = 0.f;
    for (int ch = 0; ch < 196; ++ch) {
        s   += pnum[((size_t)(b * 196 + ch) * 3 + j) * DIM + tid];
        den += pden[(b * 196 + ch) * 3 + j];
    }
    float v = s / (den + 1e-9f);
    float mu, rs;
    block_meanvar(v, mu, rs, 1e-5f);
    xn[((size_t)MROWS + blockIdx.x) * DIM + tid] = (bf16)((v - mu) * rs * g[tid] + bt[tid]);
}

__device__ __forceinline__ void load_lds16(const void* g, void* l) {
    __builtin_amdgcn_global_load_lds((const __attribute__((address_space(1))) void*)g,
                                     (__attribute__((address_space(3))) void*)l, 16, 0, 0);
}

// ---------------- GEMM: C[M,N] = A[M,K] * W[N,K]^T + bias ----------------
// r7 structure + compile-time K/N full unroll (r10).
// EPI: 0 = bf16 out, 2 = bf16 out + GELU (tanh form), 3 = f32 out + f32 residual add
template <int EPI, int K, int N>
__global__ __launch_bounds__(256) void gemm_bt(
    const bf16* __restrict__ A, const bf16* __restrict__ W,
    const float* __restrict__ bias, bf16* __restrict__ Cb,
    float* __restrict__ Cf, const float* __restrict__ resid, int M)
{
    __shared__ __align__(16) char smem[49152];   // 3 x (8KB A + 8KB B); epi overlays
    const int tid = threadIdx.x;
    const int wv = tid >> 6, lane = tid & 63;

    // bijective XCD swizzle (m204)
    const int gx = gridDim.x;
    const int nwg = gx * (int)gridDim.y;
    int lin = blockIdx.y * gx + blockIdx.x;
    int xcd = lin & 7, loc = lin >> 3;
    int qq = nwg >> 3, rr = nwg & 7;
    int nid = (xcd < rr ? xcd * (qq + 1) : rr * (qq + 1) + (xcd - rr) * qq) + loc;
    int by = nid / gx, bx = nid - by * gx;
    const int m0 = by * 128, n0 = bx * 128;

    const int r  = tid >> 2;
    const int kb = (((tid & 3) ^ ((tid >> 3) & 3)) * 8);   // pre-swizzled global k-slot
    const int wr = (wv >> 1) * 64, wc = (wv & 1) * 64;
    const int fr = lane & 15;
    const int fo = (((lane >> 4) ^ ((fr >> 1) & 3)) * 8);  // swizzled read k-slot

    int ra0 = m0 + r;      if (ra0 >= M) ra0 = M - 1;
    int ra1 = m0 + r + 64; if (ra1 >= M) ra1 = M - 1;
    const bf16* pA0 = A + (size_t)ra0 * K + kb;
    const bf16* pA1 = A + (size_t)ra1 * K + kb;
    const bf16* pW0 = W + (size_t)(n0 + r) * K + kb;
    const bf16* pW1 = W + (size_t)(n0 + r + 64) * K + kb;

    const f32x4 zero = {0.f, 0.f, 0.f, 0.f};
    f32x4 acc[4][4];
    #pragma unroll
    for (int i = 0; i < 4; ++i)
        #pragma unroll
        for (int j = 0; j < 4; ++j) acc[i][j] = zero;

    constexpr int nK = K >> 5;

    auto stage = [&](int kt, int b) {
        bf16* Ab = (bf16*)(smem + b * 16384);
        bf16* Bb = (bf16*)(smem + b * 16384 + 8192);
        const int off = kt * 32;
        load_lds16(pA0 + off, Ab + wv * 512);
        load_lds16(pA1 + off, Ab + 2048 + wv * 512);
        load_lds16(pW0 + off, Bb + wv * 512);
        load_lds16(pW1 + off, Bb + 2048 + wv * 512);
    };

    stage(0, 0);
    stage(1, 1);

    #pragma unroll
    for (int kt = 0; kt < nK; ++kt) {
        const int cur = kt % 3;                  // compile-time after unroll
        asm volatile("s_waitcnt lgkmcnt(0)" ::: "memory");
        if (kt < nK - 1) asm volatile("s_waitcnt vmcnt(4)" ::: "memory");
        else             asm volatile("s_waitcnt vmcnt(0)" ::: "memory");
        __builtin_amdgcn_s_barrier();
        if (kt + 2 < nK) stage(kt + 2, (kt + 2) % 3);
        const bf16* Ac = (const bf16*)(smem + cur * 16384);
        const bf16* Bc = (const bf16*)(smem + cur * 16384 + 8192);
        bf16x8 af[4], bw[4];
        #pragma unroll
        for (int i = 0; i < 4; ++i) af[i] = *(const bf16x8*)(Ac + (wr + i * 16 + fr) * 32 + fo);
        #pragma unroll
        for (int i = 0; i < 4; ++i) bw[i] = *(const bf16x8*)(Bc + (wc + i * 16 + fr) * 32 + fo);
        #pragma unroll
        for (int i = 0; i < 4; ++i)
            #pragma unroll
            for (int j = 0; j < 4; ++j)
                acc[i][j] = __builtin_amdgcn_mfma_f32_16x16x32_bf16(af[i], bw[j], acc[i][j], 0, 0, 0);
    }
    __syncthreads();

    const int cr = (lane >> 4) * 4, cc = lane & 15;
    if constexpr (EPI == 3) {
        float* Cs = (float*)smem;                // [64][132]
        #pragma unroll
        for (int half = 0; half < 2; ++half) {
            if (wr == half * 64) {
                #pragma unroll
                for (int i = 0; i < 4; ++i)
                    #pragma unroll
                    for (int j = 0; j < 4; ++j) {
                        const int col = wc + j * 16 + cc;
                        const float bv = bias[n0 + col];
                        #pragma unroll
                        for (int q = 0; q < 4; ++q)
                            Cs[(i * 16 + cr + q) * 132 + col] = acc[i][j][q] + bv;
                    }
            }
            __syncthreads();
            for (int p = tid; p < 2048; p += 256) {
                const int row = p >> 5, seg = (p & 31) * 4;
                const int gr = m0 + half * 64 + row;
                if (gr < M) {
                    f32x4 v = *(const f32x4*)(Cs + row * 132 + seg);
                    const size_t o = (size_t)gr * N + n0 + seg;
                    f32x4 rv = *(const f32x4*)(resid + o);
                    *(f32x4*)(Cf + o) = v + rv;
                }
            }
            __syncthreads();
        }
    } else {
        bf16* Csb = (bf16*)smem;                 // [128][144]
        #pragma unroll
        for (int i = 0; i < 4; ++i)
            #pragma unroll
            for (int j = 0; j < 4; ++j) {
                const int col = wc + j * 16 + cc;
                const float bv = bias[n0 + col];
                #pragma unroll
                for (int q = 0; q < 4; ++q) {
                    float v = acc[i][j][q] + bv;
                    if constexpr (EPI == 2) {
                        float u = 0.7978845608028654f * (v + 0.044715f * v * v * v);
                        v = v / (1.f + __expf(-2.f * u));
                    }
                    Csb[(wr + i * 16 + cr + q) * 144 + col] = (bf16)v;
                }
            }
        __syncthreads();
        for (int p = tid; p < 2048; p += 256) {
            const int row = p >> 4, seg = (p & 15) * 8;
            const int gr = m0 + row;
            if (gr < M)
                *(bf16x8*)(Cb + (size_t)gr * N + n0 + seg) = *(const bf16x8*)(Csb + row * 144 + seg);
        }
    }
}

// ---------------- fused proj GEMM + residual + LN2 (row-per-wave epilogue) ----------------
__global__ __launch_bounds__(256) void proj_ln2(
    const bf16* __restrict__ A, const bf16* __restrict__ W,
    const float* __restrict__ bias, const float* __restrict__ x,
    const float* __restrict__ g, const float* __restrict__ bt,
    float* __restrict__ x2, bf16* __restrict__ ln2)
{
    __shared__ __align__(16) char smem[40960];
    bf16* As = (bf16*)smem;
    bf16* Bs = (bf16*)(smem + 8192);

    const int tid = threadIdx.x;
    const int wv = tid >> 6, lane = tid & 63;
    const int m0 = blockIdx.x * 64;

    const int r4 = tid >> 2;
    const int kb = (((tid & 3) ^ ((tid >> 3) & 3)) * 8);
    const int fr = lane & 15;
    const int fo = (((lane >> 4) ^ ((fr >> 1) & 3)) * 8);

    const bf16* pA  = A + (size_t)(m0 + r4) * 256 + kb;
    const bf16* pW0 = W + (size_t)(r4)       * 256 + kb;
    const bf16* pW1 = W + (size_t)(r4 + 64)  * 256 + kb;
    const bf16* pW2 = W + (size_t)(r4 + 128) * 256 + kb;
    const bf16* pW3 = W + (size_t)(r4 + 192) * 256 + kb;

    const f32x4 zero = {0.f, 0.f, 0.f, 0.f};
    f32x4 acc[4][4];
    #pragma unroll
    for (int i = 0; i < 4; ++i)
        #pragma unroll
        for (int j = 0; j < 4; ++j) acc[i][j] = zero;

    auto stage = [&](int kt, int b) {
        const int off = kt * 32;
        load_lds16(pA  + off, As + b * 2048 + wv * 512);
        load_lds16(pW0 + off, Bs + b * 8192 + wv * 512);
        load_lds16(pW1 + off, Bs + b * 8192 + 2048 + wv * 512);
        load_lds16(pW2 + off, Bs + b * 8192 + 4096 + wv * 512);
        load_lds16(pW3 + off, Bs + b * 8192 + 6144 + wv * 512);
    };

    stage(0, 0);
    __syncthreads();
    #pragma unroll
    for (int kt = 0; kt < 8; ++kt) {
        const int cur = kt & 1;
        if (kt + 1 < 8) stage(kt + 1, cur ^ 1);
        const bf16* Ac = As + cur * 2048;
        const bf16* Bc = Bs + cur * 8192;
        bf16x8 af[4], bw[4];
        #pragma unroll
        for (int i = 0; i < 4; ++i) af[i] = *(const bf16x8*)(Ac + (i * 16 + fr) * 32 + fo);
        #pragma unroll
        for (int j = 0; j < 4; ++j) bw[j] = *(const bf16x8*)(Bc + (wv * 64 + j * 16 + fr) * 32 + fo);
        #pragma unroll
        for (int i = 0; i < 4; ++i)
            #pragma unroll
            for (int j = 0; j < 4; ++j)
                acc[i][j] = __builtin_amdgcn_mfma_f32_16x16x32_bf16(af[i], bw[j], acc[i][j], 0, 0, 0);
        __syncthreads();
    }

    // ---- epilogue: stage 32-row halves as f32 [32][260]; one wave per row ----
    float* Cs = (float*)smem;                    // [32][260] = 33.3 KB
    const int cr = (lane >> 4) * 4, cc = lane & 15;
    const f32x4 gv  = *(const f32x4*)(g  + lane * 4);
    const f32x4 bv2 = *(const f32x4*)(bt + lane * 4);
    #pragma unroll
    for (int h = 0; h < 2; ++h) {
        #pragma unroll
        for (int i2 = 0; i2 < 2; ++i2) {
            const int i = h * 2 + i2;
            #pragma unroll
            for (int j = 0; j < 4; ++j) {
                const int col = wv * 64 + j * 16 + cc;
                const float bv = bias[col];
                #pragma unroll
                for (int q = 0; q < 4; ++q)
                    Cs[(i2 * 16 + cr + q) * 260 + col] = acc[i][j][q] + bv;
            }
        }
        __syncthreads();
        #pragma unroll
        for (int it = 0; it < 8; ++it) {
            const int rl = wv * 8 + it;          // 0..31
            const int ar = m0 + h * 32 + rl;
            int bwin = ar / 49;
            int n = ar - bwin * 49;
            int bb = bwin >> 8, w = bwin & 255;
            int ni = n / 7, nj = n - ni * 7;
            int hh = (w >> 4) * 7 + ni + 3;  if (hh >= 112) hh -= 112;
            int ww2 = (w & 15) * 7 + nj + 3; if (ww2 >= 112) ww2 -= 112;
            const size_t nrow = (size_t)(bb * LTOT + hh * 112 + ww2);
            f32x4 pv = *(const f32x4*)(Cs + rl * 260 + lane * 4);
            f32x4 xv = *(const f32x4*)(x + nrow * 256 + lane * 4);
            f32x4 v = pv + xv;
            float s1 = v[0] + v[1] + v[2] + v[3];
            float s2 = v[0]*v[0] + v[1]*v[1] + v[2]*v[2] + v[3]*v[3];
            #pragma unroll
            for (int o = 32; o >= 1; o >>= 1) { s1 += __shfl_xor(s1, o); s2 += __shfl_xor(s2, o); }
            float mu = s1 * (1.f / 256.f);
            float rs = rsqrtf(s2 * (1.f / 256.f) - mu * mu + 1e-5f);
            *(f32x4*)(x2 + nrow * 256 + lane * 4) = v;
            bf16x4 ov;
            #pragma unroll
            for (int u = 0; u < 4; ++u) ov[u] = (bf16)((v[u] - mu) * rs * gv[u] + bv2[u]);
            *(bf16x4*)(ln2 + nrow * 256 + lane * 4) = ov;
        }
        __syncthreads();
    }
}

// ---------------- windowed attention (+ fused prior-highway blocks) ----------------
// LDS ~53 KB; launch_bounds (512,2): natural VGPR (~88), NO forced cap (r13 spill lesson).
__device__ __forceinline__ unsigned pk2(float a, float b) {
    union { bf16 h[2]; unsigned u; } c;
    c.h[0] = (bf16)a; c.h[1] = (bf16)b;
    return c.u;
}

__global__ __launch_bounds__(512, 2) void attn_kernel(
    const bf16* __restrict__ qkv, const float* __restrict__ mask,
    const float* __restrict__ rel, bf16* __restrict__ att_out,
    const float* __restrict__ pw, const float* __restrict__ pb,
    float* __restrict__ vhw_out)
{
    const int tid = threadIdx.x;
    const int bw = blockIdx.x;

    if (bw >= 1024) {                            // ---- prior highway V -> proj ----
        if (tid < 256) {
            const int rowI = bw - 1024;
            const bf16* vp = qkv + (size_t)(MROWS + rowI) * 768 + 512;
            const float* wr_ = pw + (size_t)tid * DIM;
            float acc = pb[tid];
            for (int k = 0; k < DIM; ++k) acc += (float)vp[k] * wr_[k];
            vhw_out[(size_t)rowI * DIM + tid] = acc;
        }
        return;
    }

    __shared__ int rowtab[52];
    __shared__ float mLds[49 * 53];              // 10,388 B
    __shared__ float rLds[1376];                 //  5,504 B
    __shared__ __align__(16) bf16 vT[256 * 72];  // 36,864 B

    const int b = bw >> 8, w = bw & 255;
    const int wh = w >> 4, wwi = w & 15;

    if (tid < 52) {
        int row;
        if (tid < 49) {
            int i = tid / 7, j = tid % 7;
            int gh = wh * 7 + i + 3;  if (gh >= 112) gh -= 112;
            int gw = wwi * 7 + j + 3; if (gw >= 112) gw -= 112;
            row = b * LTOT + gh * 112 + gw;
        } else {
            row = MROWS + b * 3 + (tid - 49);
        }
        rowtab[tid] = row;
    }
    __syncthreads();

    for (int e = tid; e < 49 * 53; e += 512) {
        int q = e / 53, k = e % 53;
        mLds[e] = (k < 49) ? mask[(size_t)w * 2401 + q * 49 + k] : 0.f;
    }
    for (int e = tid; e < 1376; e += 512) rLds[e] = rel[e];
    for (int e = tid; e < 256 * 12; e += 512) {
        int rr = e / 12, c = 52 + e % 12;
        vT[rr * 72 + c] = (bf16)0.f;
    }
    for (int e = tid; e < 52 * 256; e += 512) {
        int key = e >> 8, c = e & 255;
        vT[c * 72 + key] = qkv[(size_t)rowtab[key] * 768 + 512 + c];
    }
    __syncthreads();

    const int h    = tid >> 6;
    const int lane = tid & 63;
    const int cl   = lane & 15;
    const int hi4  = lane >> 4;
    const int cr   = hi4 * 4;
    const int fo   = hi4 * 8;

    // --- QK^T (S^T = K x Q) ---
    bf16x8 kf[4], qf[4];
    #pragma unroll
    for (int i = 0; i < 4; ++i) {
        int key = 16 * i + cl; if (key > 51) key = 51;
        kf[i] = *(const bf16x8*)(qkv + (size_t)rowtab[key] * 768 + 256 + h * 32 + fo);
    }
    #pragma unroll
    for (int j = 0; j < 4; ++j) {
        int qq = 16 * j + cl; if (qq > 48) qq = 48;
        qf[j] = *(const bf16x8*)(qkv + (size_t)rowtab[qq] * 768 + h * 32 + fo);
    }
    const f32x4 zero = {0.f, 0.f, 0.f, 0.f};
    f32x4 acc[4][4];
    #pragma unroll
    for (int i = 0; i < 4; ++i)
        #pragma unroll
        for (int j = 0; j < 4; ++j) acc[i][j] = zero;
    __builtin_amdgcn_s_setprio(1);
    #pragma unroll
    for (int i = 0; i < 4; ++i)
        #pragma unroll
        for (int j = 0; j < 4; ++j)
            acc[i][j] = __builtin_amdgcn_mfma_f32_16x16x32_bf16(kf[i], qf[j], acc[i][j], 0, 0, 0);
    __builtin_amdgcn_s_setprio(0);

    int kb[4][4];
    #pragma unroll
    for (int i = 0; i < 4; ++i)
        #pragma unroll
        for (int r = 0; r < 4; ++r) {
            int key = 16 * i + cr + r;
            kb[i][r] = (key / 7) * 13 + (key % 7);
        }

    f32x4 oacc[4][2];
    #pragma unroll
    for (int i = 0; i < 4; ++i) { oacc[i][0] = zero; oacc[i][1] = zero; }

    // --- per q-tile: softmax -> pack -> shfl-redistribute -> PV ---
    #pragma unroll
    for (int j = 0; j < 4; ++j) {
        const int q = 16 * j + cl;
        const int qc = q > 48 ? 48 : q;          // clamp: q>=49 lanes are discarded later
        const int i1 = q / 7, j1 = q % 7;
        const int qb = (i1 + 6) * 13 + (j1 + 6);
        float sv[16];
        float mx = -3e38f;
        #pragma unroll
        for (int i = 0; i < 4; ++i)
            #pragma unroll
            for (int r = 0; r < 4; ++r) {
                int key = 16 * i + cr + r;
                int idx = key < 49 ? (qb - kb[i][r]) : (169 + key - 49);
                idx = idx < 0 ? 0 : (idx > 171 ? 171 : idx);
                float s = acc[i][j][r] * 0.17677669529663687f
                        + mLds[qc * 53 + key] + rLds[idx * 8 + h];
                if (key >= 52) s = -3e38f;
                sv[i * 4 + r] = s;
                mx = fmaxf(mx, s);
            }
        mx = fmaxf(mx, __shfl_xor(mx, 16));
        mx = fmaxf(mx, __shfl_xor(mx, 32));
        float sum = 0.f;
        #pragma unroll
        for (int e = 0; e < 16; ++e) { float p = __expf(sv[e] - mx); sv[e] = p; sum += p; }
        sum += __shfl_xor(sum, 16);
        sum += __shfl_xor(sum, 32);
        const float inv = 1.f / sum;

        int Dw[4][2];
        #pragma unroll
        for (int i = 0; i < 4; ++i) {
            Dw[i][0] = pk2(sv[i * 4 + 0] * inv, sv[i * 4 + 1] * inv);
            Dw[i][1] = pk2(sv[i * 4 + 2] * inv, sv[i * 4 + 3] * inv);
        }
        #pragma unroll
        for (int ks = 0; ks < 2; ++ks) {
            int paw[4];
            #pragma unroll
            for (int m = 0; m < 4; ++m) {
                const int srcLane = cl + (((hi4 & 1) * 2 + (m >> 1)) << 4);
                int va = __shfl(Dw[2 * ks][m & 1], srcLane);
                int vb = __shfl(Dw[2 * ks + 1][m & 1], srcLane);
                paw[m] = (hi4 & 2) ? vb : va;
            }
            union { int w[4]; bf16x8 v; } pf;
            pf.w[0] = paw[0]; pf.w[1] = paw[1]; pf.w[2] = paw[2]; pf.w[3] = paw[3];
            bf16x8 vf0 = *(const bf16x8*)(vT + (h * 32 + cl)      * 72 + 32 * ks + fo);
            bf16x8 vf1 = *(const bf16x8*)(vT + (h * 32 + 16 + cl) * 72 + 32 * ks + fo);
            __builtin_amdgcn_s_setprio(1);
            oacc[j][0] = __builtin_amdgcn_mfma_f32_16x16x32_bf16(pf.v, vf0, oacc[j][0], 0, 0, 0);
            oacc[j][1] = __builtin_amdgcn_mfma_f32_16x16x32_bf16(pf.v, vf1, oacc[j][1], 0, 0, 0);
            __builtin_amdgcn_s_setprio(0);
        }
    }

    #pragma unroll
    for (int i = 0; i < 4; ++i)
        #pragma unroll
        for (int r = 0; r < 4; ++r) {
            int q = 16 * i + cr + r;
            if (q < 49) {
                bf16* op = att_out + ((size_t)bw * 49 + q) * 256 + h * 32 + cl;
                op[0]  = (bf16)oacc[i][0][r];
                op[16] = (bf16)oacc[i][1][r];
            }
        }
}

// ---------------- launch ----------------
extern "C" void kernel_launch(void* const* d_in, const int* in_sizes, int n_in,
                              void* d_out, int out_size, void* d_ws, size_t ws_size,
                              hipStream_t stream)
{
    const float* x     = (const float*)d_in[0];
    const float* mask  = (const float*)d_in[1];
    const float* afg   = (const float*)d_in[2];
    const float* abg   = (const float*)d_in[3];
    const float* auk   = (const float*)d_in[4];
    const float* n1g   = (const float*)d_in[5];
    const float* n1b   = (const float*)d_in[6];
    const float* n2g   = (const float*)d_in[7];
    const float* n2b   = (const float*)d_in[8];
    const float* qkvw  = (const float*)d_in[9];
    const float* qkvb  = (const float*)d_in[10];
    const float* projw = (const float*)d_in[11];
    const float* projb = (const float*)d_in[12];
    const float* rel   = (const float*)d_in[13];
    const float* fc1w  = (const float*)d_in[14];
    const float* fc1b  = (const float*)d_in[15];
    const float* fc2w  = (const float*)d_in[16];
    const float* fc2b  = (const float*)d_in[17];
    float* out = (float*)d_out;
    char*  ws  = (char*)d_ws;

    // ws map: 0..1.5MiB weights | 2MiB: xn -> atto -> hbuf (98MiB region)
    //         28MiB: qkvo (73.5MiB, dead after attn) | 102MiB: pnum/pden -> ln2b
    //         x2 residual lives in `out` (f32, separate allocation).
    bf16*  wq   = (bf16*)(ws + 0);
    bf16*  wp   = (bf16*)(ws + 393216);
    bf16*  wf1  = (bf16*)(ws + 524288);
    bf16*  wf2  = (bf16*)(ws + 1048576);
    float* pnum = (float*)(ws + (102ull << 20));
    float* pden = (float*)(ws + (102ull << 20) + 2408448);
    bf16* xn    = (bf16*)(ws + (2ull << 20));
    bf16* atto  = (bf16*)(ws + (2ull << 20));
    bf16* hbuf  = (bf16*)(ws + (2ull << 20));
    bf16* qkvo  = (bf16*)(ws + (28ull << 20));
    bf16* ln2b  = (bf16*)(ws + (102ull << 20));

    prologue<<<2320, 512, 0, stream>>>(qkvw, projw, fc1w, fc2w, (bf16*)ws,
                                       x, afg, abg, auk, pnum, pden, n1g, n1b, xn);
    prior_ln<<<12, 256, 0, stream>>>(pnum, pden, n1g, n1b, xn);

    gemm_bt<0, 256, 768><<<dim3(6, 393), 256, 0, stream>>>(xn, wq, qkvb, qkvo, nullptr, nullptr, MQKV);

    attn_kernel<<<1024 + 12, 512, 0, stream>>>(qkvo, mask, rel, atto,
                                               projw, projb, out + (size_t)MROWS * DIM);

    proj_ln2<<<MROWS / 64, 256, 0, stream>>>(atto, wp, projb, x, n2g, n2b, out, ln2b);

    gemm_bt<2, 256, 1024><<<dim3(8, 392), 256, 0, stream>>>(ln2b, wf1, fc1b, hbuf, nullptr, nullptr, MROWS);

    gemm_bt<3, 1024, 256><<<dim3(2, 392), 256, 0, stream>>>(hbuf, wf2, fc2b, nullptr, out, out, MROWS);

    (void)in_sizes; (void)n_in; (void)out_size; (void)ws_size;
}

// Round 19
// 266.979 us; speedup vs baseline: 1.0109x; 1.0109x over previous
//
#include <hip/hip_runtime.h>
#include <hip/hip_bf16.h>
#include <math.h>

typedef __bf16 bf16;
typedef bf16 bf16x8 __attribute__((ext_vector_type(8)));
typedef bf16 bf16x4 __attribute__((ext_vector_type(4)));
typedef float f32x4 __attribute__((ext_vector_type(4)));

constexpr int DIM   = 256;
constexpr int NH    = 8;
constexpr int LTOT  = 112 * 112;        // 12544
constexpr int BTOT  = 4;
constexpr int MROWS = BTOT * LTOT;      // 50176
constexpr int MQKV  = MROWS + BTOT * 3; // 50188
constexpr int NTOK  = 49;
constexpr int NKV   = 52;

// ---------------- fused prologue: weight cvt + pool partials + LN1 ----------------
__global__ __launch_bounds__(512) void prologue(
    const float* __restrict__ qkvw, const float* __restrict__ projw,
    const float* __restrict__ fc1w, const float* __restrict__ fc2w,
    bf16* __restrict__ wdst,
    const float* __restrict__ x, const float* __restrict__ afg,
    const float* __restrict__ abg, const float* __restrict__ auk,
    float* __restrict__ pnum, float* __restrict__ pden,
    const float* __restrict__ g, const float* __restrict__ bt,
    bf16* __restrict__ xn)
{
    const int blk = blockIdx.x;
    const int tid = threadIdx.x;
    if (blk < 1536) {                            // ---- weight conversion ----
        int i = blk * 512 + tid;
        float v;
        if (i < 196608)      v = qkvw[i];
        else if (i < 262144) v = projw[i - 196608];
        else if (i < 524288) v = fc1w[i - 262144];
        else                 v = fc2w[i - 524288];
        wdst[i] = (bf16)v;
        return;
    }
    if (blk < 2320) {                            // ---- pool partials ----
        const int pb = blk - 1536;
        const int b = pb / 196, ch = pb % 196;
        const int p0 = ch * 64;
        __shared__ float su[64], sf[64], sb[64];
        if (tid < 64) {
            int p = p0 + tid;
            su[tid] = auk[b * LTOT + p];
            sf[tid] = afg[b * LTOT + p];
            sb[tid] = abg[b * LTOT + p];
        }
        __syncthreads();
        if (tid < 256) {
            float nu = 0.f, nf = 0.f, nb = 0.f;
            const float* xp = x + ((size_t)b * LTOT + p0) * DIM + tid;
            for (int pp = 0; pp < 64; ++pp) {
                float xv = xp[(size_t)pp * DIM];
                nu += su[pp] * xv; nf += sf[pp] * xv; nb += sb[pp] * xv;
            }
            size_t base = (size_t)pb * 3 * DIM + tid;
            pnum[base]           = nu;
            pnum[base + DIM]     = nf;
            pnum[base + 2 * DIM] = nb;
            if (tid < 3) {
                const float* sptr = tid == 0 ? su : (tid == 1 ? sf : sb);
                float t = 0.f;
                for (int i = 0; i < 64; ++i) t += sptr[i];
                pden[pb * 3 + tid] = t;
            }
        }
        return;
    }
    // ---- LN1: one wave per row ----
    const size_t row = (size_t)(blk - 2320) * 8 + (tid >> 6);
    const int lane = tid & 63;
    f32x4 v = *(const f32x4*)(x + row * DIM + lane * 4);
    float s  = v[0] + v[1] + v[2] + v[3];
    float s2 = v[0]*v[0] + v[1]*v[1] + v[2]*v[2] + v[3]*v[3];
    #pragma unroll
    for (int o = 32; o >= 1; o >>= 1) { s += __shfl_xor(s, o); s2 += __shfl_xor(s2, o); }
    float mu = s * (1.f / 256.f);
    float var = s2 * (1.f / 256.f) - mu * mu;
    float rs = rsqrtf(var + 1e-5f);
    f32x4 gv = *(const f32x4*)(g + lane * 4);
    f32x4 bv = *(const f32x4*)(bt + lane * 4);
    bf16x4 o;
    #pragma unroll
    for (int u = 0; u < 4; ++u) o[u] = (bf16)((v[u] - mu) * rs * gv[u] + bv[u]);
    *(bf16x4*)(xn + row * DIM + lane * 4) = o;
}

// ---------------- block LN helper (256 threads, one row) ----------------
__device__ __forceinline__ void block_meanvar(float v, float& mu, float& rstd, float eps) {
    float s = v, s2 = v * v;
    #pragma unroll
    for (int o = 32; o >= 1; o >>= 1) { s += __shfl_down(s, o); s2 += __shfl_down(s2, o); }
    __shared__ float ps[4], ps2[4];
    int w = threadIdx.x >> 6, ln = threadIdx.x & 63;
    if (ln == 0) { ps[w] = s; ps2[w] = s2; }
    __syncthreads();
    float S  = ps[0] + ps[1] + ps[2] + ps[3];
    float S2 = ps2[0] + ps2[1] + ps2[2] + ps2[3];
    mu = S * (1.f / 256.f);
    float var = S2 * (1.f / 256.f) - mu * mu;
    rstd = rsqrtf(var + eps);
}

// ---------------- prior reduce + LN1 -> xn rows [MROWS..MQKV) ----------------
__global__ __launch_bounds__(256) void prior_ln(
    const float* __restrict__ pnum, const float* __restrict__ pden,
    const float* __restrict__ g, const float* __restrict__ bt, bf16* __restrict__ xn)
{
    int b = blockIdx.x / 3, j = blockIdx.x % 3, tid = threadIdx.x;
    float s = 0.f, den = 0.f;
    for (int ch = 0; ch < 196; ++ch) {
        s   += pnum[((size_t)(b * 196 + ch) * 3 + j) * DIM + tid];
        den += pden[(b * 196 + ch) * 3 + j];
    }
    float v = s / (den + 1e-9f);
    float mu, rs;
    block_meanvar(v, mu, rs, 1e-5f);
    xn[((size_t)MROWS + blockIdx.x) * DIM + tid] = (bf16)((v - mu) * rs * g[tid] + bt[tid]);
}

__device__ __forceinline__ void load_lds16(const void* g, void* l) {
    __builtin_amdgcn_global_load_lds((const __attribute__((address_space(1))) void*)g,
                                     (__attribute__((address_space(3))) void*)l, 16, 0, 0);
}

// ---------------- GEMM: C[M,N] = A[M,K] * W[N,K]^T + bias ----------------
// r7 structure + compile-time K/N full unroll (r10).
// EPI: 0 = bf16 out, 2 = bf16 out + GELU (tanh form), 3 = f32 out + f32 residual add
template <int EPI, int K, int N>
__global__ __launch_bounds__(256) void gemm_bt(
    const bf16* __restrict__ A, const bf16* __restrict__ W,
    const float* __restrict__ bias, bf16* __restrict__ Cb,
    float* __restrict__ Cf, const float* __restrict__ resid, int M)
{
    __shared__ __align__(16) char smem[49152];   // 3 x (8KB A + 8KB B); epi overlays
    const int tid = threadIdx.x;
    const int wv = tid >> 6, lane = tid & 63;

    // bijective XCD swizzle (m204)
    const int gx = gridDim.x;
    const int nwg = gx * (int)gridDim.y;
    int lin = blockIdx.y * gx + blockIdx.x;
    int xcd = lin & 7, loc = lin >> 3;
    int qq = nwg >> 3, rr = nwg & 7;
    int nid = (xcd < rr ? xcd * (qq + 1) : rr * (qq + 1) + (xcd - rr) * qq) + loc;
    int by = nid / gx, bx = nid - by * gx;
    const int m0 = by * 128, n0 = bx * 128;

    const int r  = tid >> 2;
    const int kb = (((tid & 3) ^ ((tid >> 3) & 3)) * 8);   // pre-swizzled global k-slot
    const int wr = (wv >> 1) * 64, wc = (wv & 1) * 64;
    const int fr = lane & 15;
    const int fo = (((lane >> 4) ^ ((fr >> 1) & 3)) * 8);  // swizzled read k-slot

    int ra0 = m0 + r;      if (ra0 >= M) ra0 = M - 1;
    int ra1 = m0 + r + 64; if (ra1 >= M) ra1 = M - 1;
    const bf16* pA0 = A + (size_t)ra0 * K + kb;
    const bf16* pA1 = A + (size_t)ra1 * K + kb;
    const bf16* pW0 = W + (size_t)(n0 + r) * K + kb;
    const bf16* pW1 = W + (size_t)(n0 + r + 64) * K + kb;

    const f32x4 zero = {0.f, 0.f, 0.f, 0.f};
    f32x4 acc[4][4];
    #pragma unroll
    for (int i = 0; i < 4; ++i)
        #pragma unroll
        for (int j = 0; j < 4; ++j) acc[i][j] = zero;

    constexpr int nK = K >> 5;

    auto stage = [&](int kt, int b) {
        bf16* Ab = (bf16*)(smem + b * 16384);
        bf16* Bb = (bf16*)(smem + b * 16384 + 8192);
        const int off = kt * 32;
        load_lds16(pA0 + off, Ab + wv * 512);
        load_lds16(pA1 + off, Ab + 2048 + wv * 512);
        load_lds16(pW0 + off, Bb + wv * 512);
        load_lds16(pW1 + off, Bb + 2048 + wv * 512);
    };

    stage(0, 0);
    stage(1, 1);

    #pragma unroll
    for (int kt = 0; kt < nK; ++kt) {
        const int cur = kt % 3;                  // compile-time after unroll
        asm volatile("s_waitcnt lgkmcnt(0)" ::: "memory");
        if (kt < nK - 1) asm volatile("s_waitcnt vmcnt(4)" ::: "memory");
        else             asm volatile("s_waitcnt vmcnt(0)" ::: "memory");
        __builtin_amdgcn_s_barrier();
        if (kt + 2 < nK) stage(kt + 2, (kt + 2) % 3);
        const bf16* Ac = (const bf16*)(smem + cur * 16384);
        const bf16* Bc = (const bf16*)(smem + cur * 16384 + 8192);
        bf16x8 af[4], bw[4];
        #pragma unroll
        for (int i = 0; i < 4; ++i) af[i] = *(const bf16x8*)(Ac + (wr + i * 16 + fr) * 32 + fo);
        #pragma unroll
        for (int i = 0; i < 4; ++i) bw[i] = *(const bf16x8*)(Bc + (wc + i * 16 + fr) * 32 + fo);
        #pragma unroll
        for (int i = 0; i < 4; ++i)
            #pragma unroll
            for (int j = 0; j < 4; ++j)
                acc[i][j] = __builtin_amdgcn_mfma_f32_16x16x32_bf16(af[i], bw[j], acc[i][j], 0, 0, 0);
    }
    __syncthreads();

    const int cr = (lane >> 4) * 4, cc = lane & 15;
    if constexpr (EPI == 3) {
        float* Cs = (float*)smem;                // [64][132]
        #pragma unroll
        for (int half = 0; half < 2; ++half) {
            if (wr == half * 64) {
                #pragma unroll
                for (int i = 0; i < 4; ++i)
                    #pragma unroll
                    for (int j = 0; j < 4; ++j) {
                        const int col = wc + j * 16 + cc;
                        const float bv = bias[n0 + col];
                        #pragma unroll
                        for (int q = 0; q < 4; ++q)
                            Cs[(i * 16 + cr + q) * 132 + col] = acc[i][j][q] + bv;
                    }
            }
            __syncthreads();
            for (int p = tid; p < 2048; p += 256) {
                const int row = p >> 5, seg = (p & 31) * 4;
                const int gr = m0 + half * 64 + row;
                if (gr < M) {
                    f32x4 v = *(const f32x4*)(Cs + row * 132 + seg);
                    const size_t o = (size_t)gr * N + n0 + seg;
                    f32x4 rv = *(const f32x4*)(resid + o);
                    *(f32x4*)(Cf + o) = v + rv;
                }
            }
            __syncthreads();
        }
    } else {
        bf16* Csb = (bf16*)smem;                 // [128][144]
        #pragma unroll
        for (int i = 0; i < 4; ++i)
            #pragma unroll
            for (int j = 0; j < 4; ++j) {
                const int col = wc + j * 16 + cc;
                const float bv = bias[n0 + col];
                #pragma unroll
                for (int q = 0; q < 4; ++q) {
                    float v = acc[i][j][q] + bv;
                    if constexpr (EPI == 2) {
                        float u = 0.7978845608028654f * (v + 0.044715f * v * v * v);
                        v = v / (1.f + __expf(-2.f * u));
                    }
                    Csb[(wr + i * 16 + cr + q) * 144 + col] = (bf16)v;
                }
            }
        __syncthreads();
        for (int p = tid; p < 2048; p += 256) {
            const int row = p >> 4, seg = (p & 15) * 8;
            const int gr = m0 + row;
            if (gr < M)
                *(bf16x8*)(Cb + (size_t)gr * N + n0 + seg) = *(const bf16x8*)(Csb + row * 144 + seg);
        }
    }
}

// ---------------- fused proj GEMM + residual + LN2 (row-per-wave epilogue) ----------------
__global__ __launch_bounds__(256) void proj_ln2(
    const bf16* __restrict__ A, const bf16* __restrict__ W,
    const float* __restrict__ bias, const float* __restrict__ x,
    const float* __restrict__ g, const float* __restrict__ bt,
    float* __restrict__ x2, bf16* __restrict__ ln2)
{
    __shared__ __align__(16) char smem[40960];
    bf16* As = (bf16*)smem;
    bf16* Bs = (bf16*)(smem + 8192);

    const int tid = threadIdx.x;
    const int wv = tid >> 6, lane = tid & 63;
    const int m0 = blockIdx.x * 64;

    const int r4 = tid >> 2;
    const int kb = (((tid & 3) ^ ((tid >> 3) & 3)) * 8);
    const int fr = lane & 15;
    const int fo = (((lane >> 4) ^ ((fr >> 1) & 3)) * 8);

    const bf16* pA  = A + (size_t)(m0 + r4) * 256 + kb;
    const bf16* pW0 = W + (size_t)(r4)       * 256 + kb;
    const bf16* pW1 = W + (size_t)(r4 + 64)  * 256 + kb;
    const bf16* pW2 = W + (size_t)(r4 + 128) * 256 + kb;
    const bf16* pW3 = W + (size_t)(r4 + 192) * 256 + kb;

    const f32x4 zero = {0.f, 0.f, 0.f, 0.f};
    f32x4 acc[4][4];
    #pragma unroll
    for (int i = 0; i < 4; ++i)
        #pragma unroll
        for (int j = 0; j < 4; ++j) acc[i][j] = zero;

    auto stage = [&](int kt, int b) {
        const int off = kt * 32;
        load_lds16(pA  + off, As + b * 2048 + wv * 512);
        load_lds16(pW0 + off, Bs + b * 8192 + wv * 512);
        load_lds16(pW1 + off, Bs + b * 8192 + 2048 + wv * 512);
        load_lds16(pW2 + off, Bs + b * 8192 + 4096 + wv * 512);
        load_lds16(pW3 + off, Bs + b * 8192 + 6144 + wv * 512);
    };

    stage(0, 0);
    __syncthreads();
    #pragma unroll
    for (int kt = 0; kt < 8; ++kt) {
        const int cur = kt & 1;
        if (kt + 1 < 8) stage(kt + 1, cur ^ 1);
        const bf16* Ac = As + cur * 2048;
        const bf16* Bc = Bs + cur * 8192;
        bf16x8 af[4], bw[4];
        #pragma unroll
        for (int i = 0; i < 4; ++i) af[i] = *(const bf16x8*)(Ac + (i * 16 + fr) * 32 + fo);
        #pragma unroll
        for (int j = 0; j < 4; ++j) bw[j] = *(const bf16x8*)(Bc + (wv * 64 + j * 16 + fr) * 32 + fo);
        #pragma unroll
        for (int i = 0; i < 4; ++i)
            #pragma unroll
            for (int j = 0; j < 4; ++j)
                acc[i][j] = __builtin_amdgcn_mfma_f32_16x16x32_bf16(af[i], bw[j], acc[i][j], 0, 0, 0);
        __syncthreads();
    }

    // ---- epilogue: stage 32-row halves as f32 [32][260]; one wave per row ----
    float* Cs = (float*)smem;                    // [32][260] = 33.3 KB
    const int cr = (lane >> 4) * 4, cc = lane & 15;
    const f32x4 gv  = *(const f32x4*)(g  + lane * 4);
    const f32x4 bv2 = *(const f32x4*)(bt + lane * 4);
    #pragma unroll
    for (int h = 0; h < 2; ++h) {
        #pragma unroll
        for (int i2 = 0; i2 < 2; ++i2) {
            const int i = h * 2 + i2;
            #pragma unroll
            for (int j = 0; j < 4; ++j) {
                const int col = wv * 64 + j * 16 + cc;
                const float bv = bias[col];
                #pragma unroll
                for (int q = 0; q < 4; ++q)
                    Cs[(i2 * 16 + cr + q) * 260 + col] = acc[i][j][q] + bv;
            }
        }
        __syncthreads();
        #pragma unroll
        for (int it = 0; it < 8; ++it) {
            const int rl = wv * 8 + it;          // 0..31
            const int ar = m0 + h * 32 + rl;
            int bwin = ar / 49;
            int n = ar - bwin * 49;
            int bb = bwin >> 8, w = bwin & 255;
            int ni = n / 7, nj = n - ni * 7;
            int hh = (w >> 4) * 7 + ni + 3;  if (hh >= 112) hh -= 112;
            int ww2 = (w & 15) * 7 + nj + 3; if (ww2 >= 112) ww2 -= 112;
            const size_t nrow = (size_t)(bb * LTOT + hh * 112 + ww2);
            f32x4 pv = *(const f32x4*)(Cs + rl * 260 + lane * 4);
            f32x4 xv = *(const f32x4*)(x + nrow * 256 + lane * 4);
            f32x4 v = pv + xv;
            float s1 = v[0] + v[1] + v[2] + v[3];
            float s2 = v[0]*v[0] + v[1]*v[1] + v[2]*v[2] + v[3]*v[3];
            #pragma unroll
            for (int o = 32; o >= 1; o >>= 1) { s1 += __shfl_xor(s1, o); s2 += __shfl_xor(s2, o); }
            float mu = s1 * (1.f / 256.f);
            float rs = rsqrtf(s2 * (1.f / 256.f) - mu * mu + 1e-5f);
            *(f32x4*)(x2 + nrow * 256 + lane * 4) = v;
            bf16x4 ov;
            #pragma unroll
            for (int u = 0; u < 4; ++u) ov[u] = (bf16)((v[u] - mu) * rs * gv[u] + bv2[u]);
            *(bf16x4*)(ln2 + nrow * 256 + lane * 4) = ov;
        }
        __syncthreads();
    }
}

// ---------------- windowed attention (+ fused prior-highway blocks) ----------------
// LDS ~53 KB; launch_bounds (512,2): natural VGPR (~88), NO forced cap (r13 spill lesson).
__device__ __forceinline__ unsigned pk2(float a, float b) {
    union { bf16 h[2]; unsigned u; } c;
    c.h[0] = (bf16)a; c.h[1] = (bf16)b;
    return c.u;
}

__global__ __launch_bounds__(512, 2) void attn_kernel(
    const bf16* __restrict__ qkv, const float* __restrict__ mask,
    const float* __restrict__ rel, bf16* __restrict__ att_out,
    const float* __restrict__ pw, const float* __restrict__ pb,
    float* __restrict__ vhw_out)
{
    const int tid = threadIdx.x;
    const int bw = blockIdx.x;

    if (bw >= 1024) {                            // ---- prior highway V -> proj ----
        if (tid < 256) {
            const int rowI = bw - 1024;
            const bf16* vp = qkv + (size_t)(MROWS + rowI) * 768 + 512;
            const float* wr_ = pw + (size_t)tid * DIM;
            float acc = pb[tid];
            for (int k = 0; k < DIM; ++k) acc += (float)vp[k] * wr_[k];
            vhw_out[(size_t)rowI * DIM + tid] = acc;
        }
        return;
    }

    __shared__ int rowtab[52];
    __shared__ float mLds[49 * 53];              // 10,388 B
    __shared__ float rLds[1376];                 //  5,504 B
    __shared__ __align__(16) bf16 vT[256 * 72];  // 36,864 B

    const int b = bw >> 8, w = bw & 255;
    const int wh = w >> 4, wwi = w & 15;

    if (tid < 52) {
        int row;
        if (tid < 49) {
            int i = tid / 7, j = tid % 7;
            int gh = wh * 7 + i + 3;  if (gh >= 112) gh -= 112;
            int gw = wwi * 7 + j + 3; if (gw >= 112) gw -= 112;
            row = b * LTOT + gh * 112 + gw;
        } else {
            row = MROWS + b * 3 + (tid - 49);
        }
        rowtab[tid] = row;
    }
    __syncthreads();

    for (int e = tid; e < 49 * 53; e += 512) {
        int q = e / 53, k = e % 53;
        mLds[e] = (k < 49) ? mask[(size_t)w * 2401 + q * 49 + k] : 0.f;
    }
    for (int e = tid; e < 1376; e += 512) rLds[e] = rel[e];
    for (int e = tid; e < 256 * 12; e += 512) {
        int rr = e / 12, c = 52 + e % 12;
        vT[rr * 72 + c] = (bf16)0.f;
    }
    for (int e = tid; e < 52 * 256; e += 512) {
        int key = e >> 8, c = e & 255;
        vT[c * 72 + key] = qkv[(size_t)rowtab[key] * 768 + 512 + c];
    }
    __syncthreads();

    const int h    = tid >> 6;
    const int lane = tid & 63;
    const int cl   = lane & 15;
    const int hi4  = lane >> 4;
    const int cr   = hi4 * 4;
    const int fo   = hi4 * 8;

    // --- QK^T (S^T = K x Q) ---
    bf16x8 kf[4], qf[4];
    #pragma unroll
    for (int i = 0; i < 4; ++i) {
        int key = 16 * i + cl; if (key > 51) key = 51;
        kf[i] = *(const bf16x8*)(qkv + (size_t)rowtab[key] * 768 + 256 + h * 32 + fo);
    }
    #pragma unroll
    for (int j = 0; j < 4; ++j) {
        int qq = 16 * j + cl; if (qq > 48) qq = 48;
        qf[j] = *(const bf16x8*)(qkv + (size_t)rowtab[qq] * 768 + h * 32 + fo);
    }
    const f32x4 zero = {0.f, 0.f, 0.f, 0.f};
    f32x4 acc[4][4];
    #pragma unroll
    for (int i = 0; i < 4; ++i)
        #pragma unroll
        for (int j = 0; j < 4; ++j) acc[i][j] = zero;
    __builtin_amdgcn_s_setprio(1);
    #pragma unroll
    for (int i = 0; i < 4; ++i)
        #pragma unroll
        for (int j = 0; j < 4; ++j)
            acc[i][j] = __builtin_amdgcn_mfma_f32_16x16x32_bf16(kf[i], qf[j], acc[i][j], 0, 0, 0);
    __builtin_amdgcn_s_setprio(0);

    int kb[4][4];
    #pragma unroll
    for (int i = 0; i < 4; ++i)
        #pragma unroll
        for (int r = 0; r < 4; ++r) {
            int key = 16 * i + cr + r;
            kb[i][r] = (key / 7) * 13 + (key % 7);
        }

    f32x4 oacc[4][2];
    #pragma unroll
    for (int i = 0; i < 4; ++i) { oacc[i][0] = zero; oacc[i][1] = zero; }

    // --- per q-tile: softmax -> pack -> shfl-redistribute -> PV ---
    #pragma unroll
    for (int j = 0; j < 4; ++j) {
        const int q = 16 * j + cl;
        const int qc = q > 48 ? 48 : q;          // clamp: q>=49 lanes are discarded later
        const int i1 = q / 7, j1 = q % 7;
        const int qb = (i1 + 6) * 13 + (j1 + 6);
        float sv[16];
        float mx = -3e38f;
        #pragma unroll
        for (int i = 0; i < 4; ++i)
            #pragma unroll
            for (int r = 0; r < 4; ++r) {
                int key = 16 * i + cr + r;
                int idx = key < 49 ? (qb - kb[i][r]) : (169 + key - 49);
                idx = idx < 0 ? 0 : (idx > 171 ? 171 : idx);
                float s = acc[i][j][r] * 0.17677669529663687f
                        + mLds[qc * 53 + key] + rLds[idx * 8 + h];
                if (key >= 52) s = -3e38f;
                sv[i * 4 + r] = s;
                mx = fmaxf(mx, s);
            }
        mx = fmaxf(mx, __shfl_xor(mx, 16));
        mx = fmaxf(mx, __shfl_xor(mx, 32));
        float sum = 0.f;
        #pragma unroll
        for (int e = 0; e < 16; ++e) { float p = __expf(sv[e] - mx); sv[e] = p; sum += p; }
        sum += __shfl_xor(sum, 16);
        sum += __shfl_xor(sum, 32);
        const float inv = 1.f / sum;

        int Dw[4][2];
        #pragma unroll
        for (int i = 0; i < 4; ++i) {
            Dw[i][0] = pk2(sv[i * 4 + 0] * inv, sv[i * 4 + 1] * inv);
            Dw[i][1] = pk2(sv[i * 4 + 2] * inv, sv[i * 4 + 3] * inv);
        }
        #pragma unroll
        for (int ks = 0; ks < 2; ++ks) {
            int paw[4];
            #pragma unroll
            for (int m = 0; m < 4; ++m) {
                const int srcLane = cl + (((hi4 & 1) * 2 + (m >> 1)) << 4);
                int va = __shfl(Dw[2 * ks][m & 1], srcLane);
                int vb = __shfl(Dw[2 * ks + 1][m & 1], srcLane);
                paw[m] = (hi4 & 2) ? vb : va;
            }
            union { int w[4]; bf16x8 v; } pf;
            pf.w[0] = paw[0]; pf.w[1] = paw[1]; pf.w[2] = paw[2]; pf.w[3] = paw[3];
            bf16x8 vf0 = *(const bf16x8*)(vT + (h * 32 + cl)      * 72 + 32 * ks + fo);
            bf16x8 vf1 = *(const bf16x8*)(vT + (h * 32 + 16 + cl) * 72 + 32 * ks + fo);
            __builtin_amdgcn_s_setprio(1);
            oacc[j][0] = __builtin_amdgcn_mfma_f32_16x16x32_bf16(pf.v, vf0, oacc[j][0], 0, 0, 0);
            oacc[j][1] = __builtin_amdgcn_mfma_f32_16x16x32_bf16(pf.v, vf1, oacc[j][1], 0, 0, 0);
            __builtin_amdgcn_s_setprio(0);
        }
    }

    #pragma unroll
    for (int i = 0; i < 4; ++i)
        #pragma unroll
        for (int r = 0; r < 4; ++r) {
            int q = 16 * i + cr + r;
            if (q < 49) {
                bf16* op = att_out + ((size_t)bw * 49 + q) * 256 + h * 32 + cl;
                op[0]  = (bf16)oacc[i][0][r];
                op[16] = (bf16)oacc[i][1][r];
            }
        }
}

// ---------------- launch ----------------
extern "C" void kernel_launch(void* const* d_in, const int* in_sizes, int n_in,
                              void* d_out, int out_size, void* d_ws, size_t ws_size,
                              hipStream_t stream)
{
    const float* x     = (const float*)d_in[0];
    const float* mask  = (const float*)d_in[1];
    const float* afg   = (const float*)d_in[2];
    const float* abg   = (const float*)d_in[3];
    const float* auk   = (const float*)d_in[4];
    const float* n1g   = (const float*)d_in[5];
    const float* n1b   = (const float*)d_in[6];
    const float* n2g   = (const float*)d_in[7];
    const float* n2b   = (const float*)d_in[8];
    const float* qkvw  = (const float*)d_in[9];
    const float* qkvb  = (const float*)d_in[10];
    const float* projw = (const float*)d_in[11];
    const float* projb = (const float*)d_in[12];
    const float* rel   = (const float*)d_in[13];
    const float* fc1w  = (const float*)d_in[14];
    const float* fc1b  = (const float*)d_in[15];
    const float* fc2w  = (const float*)d_in[16];
    const float* fc2b  = (const float*)d_in[17];
    float* out = (float*)d_out;
    char*  ws  = (char*)d_ws;

    // ws map: 0..1.5MiB weights | 2MiB: xn -> atto -> hbuf (98MiB region)
    //         28MiB: qkvo (73.5MiB, dead after attn) | 102MiB: pnum/pden -> ln2b
    //         x2 residual lives in `out` (f32, separate allocation).
    bf16*  wq   = (bf16*)(ws + 0);
    bf16*  wp   = (bf16*)(ws + 393216);
    bf16*  wf1  = (bf16*)(ws + 524288);
    bf16*  wf2  = (bf16*)(ws + 1048576);
    float* pnum = (float*)(ws + (102ull << 20));
    float* pden = (float*)(ws + (102ull << 20) + 2408448);
    bf16* xn    = (bf16*)(ws + (2ull << 20));
    bf16* atto  = (bf16*)(ws + (2ull << 20));
    bf16* hbuf  = (bf16*)(ws + (2ull << 20));
    bf16* qkvo  = (bf16*)(ws + (28ull << 20));
    bf16* ln2b  = (bf16*)(ws + (102ull << 20));

    prologue<<<8592, 512, 0, stream>>>(qkvw, projw, fc1w, fc2w, (bf16*)ws,
                                       x, afg, abg, auk, pnum, pden, n1g, n1b, xn);
    prior_ln<<<12, 256, 0, stream>>>(pnum, pden, n1g, n1b, xn);

    gemm_bt<0, 256, 768><<<dim3(6, 393), 256, 0, stream>>>(xn, wq, qkvb, qkvo, nullptr, nullptr, MQKV);

    attn_kernel<<<1024 + 12, 512, 0, stream>>>(qkvo, mask, rel, atto,
                                               projw, projb, out + (size_t)MROWS * DIM);

    proj_ln2<<<MROWS / 64, 256, 0, stream>>>(atto, wp, projb, x, n2g, n2b, out, ln2b);

    gemm_bt<2, 256, 1024><<<dim3(8, 392), 256, 0, stream>>>(ln2b, wf1, fc1b, hbuf, nullptr, nullptr, MROWS);

    gemm_bt<3, 1024, 256><<<dim3(2, 392), 256, 0, stream>>>(hbuf, wf2, fc2b, nullptr, out, out, MROWS);

    (void)in_sizes; (void)n_in; (void)out_size; (void)ws_size;
}